// Round 11
// baseline (86.016 us; speedup 1.0000x reference)
//
#include <hip/hip_runtime.h>
#include <math.h>

#define B_ 8
#define C_ 64
#define K_ 32
#define HW_ 16384
#define LDN 132              // padded staging row stride (floats): +1 bank-quad per row
#define NCHUNKOUT_ 32        // one partial slab per corr block (512 n each)
#define TILE_ 256            // fusion px tile
#define NEG_SLOPE_ 0.1f

// ws layout:
//   [0, 4MB)          float partial[B_][NCHUNKOUT_][C_][C_]
//   [4MB, 4MB+64KB)   int   idxb[B_][C_][K_]

// corr v8: 256 blocks x 512 n (4 chunks of 128). Software-pipelined
// reg-staging: per chunk {ds_write staged regs; barrier; issue NEXT chunk's
// global loads (VGPR); compute current from LDS; barrier} -> HBM latency
// hides under the 8x8-register-tile fma burst. n-split: wave wv computes the
// full 64x64 over n-cols [wv*32, wv*32+32). LDN=132 keeps both ds_write
// (contiguous b128) and strided-row b128 reads conflict-free.
__global__ __launch_bounds__(256, 2) void corr_partial_kernel(
    const float* __restrict__ LR, const float* __restrict__ HR,
    float* __restrict__ partial)
{
    __shared__ float smem[2 * C_ * LDN];   // 67,584 B: lrS + hrS
    float* lrS = smem;
    float* hrS = smem + C_ * LDN;

    const int bid = blockIdx.x;          // 256 = B * 32
    const int b = bid >> 5;
    const int q = bid & 31;
    const int t = threadIdx.x;
    const int wv = t >> 6;               // 0..3
    const int lane = t & 63;
    const int cq = lane >> 3;            // 0..7
    const int dq = lane & 7;             // 0..7

    // per-thread staging addresses (8 float4 per array per chunk)
    int sc[8], scol[8];
    #pragma unroll
    for (int p = 0; p < 8; ++p) {
        const int f = p * 256 + t;
        sc[p] = f >> 5;                  // 0..63
        scol[p] = (f & 31) * 4;          // 0..124
    }

    float4 sLR[8], sHR[8];
    {   // prologue: load chunk 0
        const int n0 = q * 512;
        #pragma unroll
        for (int p = 0; p < 8; ++p) {
            const size_t g = (size_t)(b * C_ + sc[p]) * HW_ + n0 + scol[p];
            sLR[p] = *reinterpret_cast<const float4*>(&LR[g]);
            sHR[p] = *reinterpret_cast<const float4*>(&HR[g]);
        }
    }

    float acc[8][8] = {};

    #pragma unroll 1
    for (int ck = 0; ck < 4; ++ck) {
        if (ck) __syncthreads();         // WAR: prev compute done before rewrite
        #pragma unroll
        for (int p = 0; p < 8; ++p) {
            *reinterpret_cast<float4*>(&lrS[sc[p] * LDN + scol[p]]) = sLR[p];
            *reinterpret_cast<float4*>(&hrS[sc[p] * LDN + scol[p]]) = sHR[p];
        }
        __syncthreads();                 // RAW: writes visible before reads

        if (ck < 3) {                    // issue next chunk's loads (overlap compute)
            const int n0 = q * 512 + (ck + 1) * 128;
            #pragma unroll
            for (int p = 0; p < 8; ++p) {
                const size_t g = (size_t)(b * C_ + sc[p]) * HW_ + n0 + scol[p];
                sLR[p] = *reinterpret_cast<const float4*>(&LR[g]);
                sHR[p] = *reinterpret_cast<const float4*>(&HR[g]);
            }
        }

        // compute: wave wv owns n-cols [wv*32, wv*32+32)
        #pragma unroll
        for (int nq = 0; nq < 8; ++nq) {
            const int col = wv * 32 + nq * 4;
            float4 lv[8];
            #pragma unroll
            for (int i = 0; i < 8; ++i)
                lv[i] = *reinterpret_cast<const float4*>(&lrS[(cq + 8 * i) * LDN + col]);
            #pragma unroll
            for (int j = 0; j < 8; ++j) {
                const float4 hv = *reinterpret_cast<const float4*>(&hrS[(dq + 8 * j) * LDN + col]);
                #pragma unroll
                for (int i = 0; i < 8; ++i) {
                    acc[i][j] = fmaf(lv[i].x, hv.x, acc[i][j]);
                    acc[i][j] = fmaf(lv[i].y, hv.y, acc[i][j]);
                    acc[i][j] = fmaf(lv[i].z, hv.z, acc[i][j]);
                    acc[i][j] = fmaf(lv[i].w, hv.w, acc[i][j]);
                }
            }
        }
    }

    // cross-wave reduction, single phase: red[w][sl][lane][4] = 64 KB.
    // slot sl (0..15) -> (i = sl>>1, j0 = (sl&1)*4).
    __syncthreads();
    float* red = smem;
    #pragma unroll
    for (int sl = 0; sl < 16; ++sl) {
        const int i = sl >> 1;
        const int j0 = (sl & 1) * 4;
        *reinterpret_cast<float4*>(&red[((wv * 16 + sl) * 64 + lane) * 4]) =
            make_float4(acc[i][j0], acc[i][j0 + 1], acc[i][j0 + 2], acc[i][j0 + 3]);
    }
    __syncthreads();

    float* P = partial + (size_t)bid * (C_ * C_);
    #pragma unroll
    for (int pp = 0; pp < 4; ++pp) {
        const int sl = wv * 4 + pp;      // this wave reduces slots [wv*4, wv*4+4)
        float4 s = make_float4(0.f, 0.f, 0.f, 0.f);
        #pragma unroll
        for (int w = 0; w < 4; ++w) {    // fixed order -> deterministic
            const float4 v = *reinterpret_cast<const float4*>(
                &red[((w * 16 + sl) * 64 + lane) * 4]);
            s.x += v.x; s.y += v.y; s.z += v.z; s.w += v.w;
        }
        const int i = sl >> 1;
        const int j0 = (sl & 1) * 4;
        const int row = (lane >> 3) + 8 * i;
        const int colb = (lane & 7) + 8 * j0;
        P[row * C_ + colb]      = s.x;
        P[row * C_ + colb + 8]  = s.y;
        P[row * C_ + colb + 16] = s.z;
        P[row * C_ + colb + 24] = s.w;
    }
}

// Reduce partials (f64, deterministic), rank channels per (b,c) like lax.top_k
// (stable descending), emit top-K channel indices.
__global__ __launch_bounds__(64) void rank_kernel(
    const float* __restrict__ partial, int* __restrict__ idxb)
{
    __shared__ double vals[C_];
    const int blk = blockIdx.x;     // b*64 + c
    const int b = blk >> 6;
    const int c = blk & 63;
    const int d = threadIdx.x;

    double acc = 0.0;
    for (int k = 0; k < NCHUNKOUT_; ++k)
        acc += (double)partial[(size_t)(b * NCHUNKOUT_ + k) * (C_ * C_) + c * C_ + d];
    vals[d] = acc;
    __syncthreads();

    int r = 0;
    for (int jj = 0; jj < C_; ++jj) {
        const double vj = vals[jj];
        r += (int)((vj > acc) || (vj == acc && jj < d));   // stable descending rank
    }
    if (r < K_) idxb[blk * K_ + r] = d;
}

// Gather fusion (unchanged, proven ~26us): stage HR[64][256] px-slab in LDS;
// 8 waves x 8 c each; gather via ds_read_b128 (1 KB/wave-instr).
__global__ __launch_bounds__(512, 2) void fusion_gather_kernel(
    const float* __restrict__ HR, const float* __restrict__ LR,
    const int* __restrict__ idxb,
    const float* __restrict__ w1, const float* __restrict__ b1,
    const float* __restrict__ w2, const float* __restrict__ b2,
    float* __restrict__ out)
{
    __shared__ float hrS[C_][TILE_];   // 64 KB

    const int t = threadIdx.x;
    const int bid = blockIdx.x;        // 512 = B * (HW/TILE)
    const int b = bid >> 6;
    const int px0 = (bid & 63) * TILE_;

    const float* HRb = HR + (size_t)b * C_ * HW_;
    #pragma unroll
    for (int i = 0; i < 8; ++i) {
        const int f = i * 512 + t;
        const int c = f >> 6;
        const int qq = f & 63;
        *reinterpret_cast<float4*>(&hrS[c][qq * 4]) =
            *reinterpret_cast<const float4*>(&HRb[(size_t)c * HW_ + px0 + qq * 4]);
    }
    __syncthreads();

    const int wv = t >> 6;             // wave id -> c-octant
    const int lane = t & 63;
    const int p4 = lane * 4;           // this lane's 4 px within the tile

    const int* idxc = idxb + b * C_ * K_;
    const float w10 = w1[0];
    const float b1v = b1[0], w2v = w2[0], b2v = b2[0];

    #pragma unroll 1
    for (int ci = 0; ci < 8; ++ci) {
        const int c = wv * 8 + ci;
        const float4 l4 = *reinterpret_cast<const float4*>(
            &LR[(size_t)(b * C_ + c) * HW_ + px0 + p4]);         // issue early
        float acc[4] = {0.f, 0.f, 0.f, 0.f};
        float mx[4]  = {-1e30f, -1e30f, -1e30f, -1e30f};
        #pragma unroll
        for (int k = 0; k < K_; ++k) {
            const int d = idxc[c * K_ + k];          // uniform -> s_load
            const float4 h = *reinterpret_cast<const float4*>(&hrS[d][p4]);
            const float wk = w1[k + 1];              // uniform -> SGPR
            acc[0] = fmaf(h.x, wk, acc[0]);
            acc[1] = fmaf(h.y, wk, acc[1]);
            acc[2] = fmaf(h.z, wk, acc[2]);
            acc[3] = fmaf(h.w, wk, acc[3]);
            mx[0] = fmaxf(mx[0], h.x);
            mx[1] = fmaxf(mx[1], h.y);
            mx[2] = fmaxf(mx[2], h.z);
            mx[3] = fmaxf(mx[3], h.w);
        }
        const float l[4] = {l4.x, l4.y, l4.z, l4.w};
        float o[4];
        #pragma unroll
        for (int p = 0; p < 4; ++p) {
            float f = fmaf(w10, l[p], acc[p]) + b1v;
            f = f >= 0.f ? f : NEG_SLOPE_ * f;
            f = fmaf(w2v, f, b2v);
            const float s = 1.f / (1.f + __expf(-mx[p]));
            o[p] = f * (1.f + s);
        }
        *reinterpret_cast<float4*>(&out[(size_t)(b * C_ + c) * HW_ + px0 + p4]) =
            make_float4(o[0], o[1], o[2], o[3]);
    }
}

extern "C" void kernel_launch(void* const* d_in, const int* in_sizes, int n_in,
                              void* d_out, int out_size, void* d_ws, size_t ws_size,
                              hipStream_t stream)
{
    const float* HR = (const float*)d_in[0];
    const float* LR = (const float*)d_in[1];
    const float* w1 = (const float*)d_in[2];
    const float* b1 = (const float*)d_in[3];
    const float* w2 = (const float*)d_in[4];
    const float* b2 = (const float*)d_in[5];
    float* out = (float*)d_out;

    float* partial = (float*)d_ws;
    int* idxb = (int*)((char*)d_ws + (size_t)B_ * NCHUNKOUT_ * C_ * C_ * sizeof(float));

    corr_partial_kernel<<<B_ * 32, 256, 0, stream>>>(LR, HR, partial);
    rank_kernel<<<B_ * C_, 64, 0, stream>>>(partial, idxb);
    fusion_gather_kernel<<<B_ * (HW_ / TILE_), 512, 0, stream>>>(HR, LR, idxb, w1, b1, w2, b2, out);
}

// Round 12
// 65.011 us; speedup vs baseline: 1.3231x; 1.3231x over previous
//
#include <hip/hip_runtime.h>
#include <math.h>

#define B_ 8
#define C_ 64
#define K_ 32
#define HW_ 16384
#define SROW 36              // padded LDS row stride (floats): +1 bank-quad per row
#define NPART_ 256           // partial slabs per batch (one per wave-task)
#define TILE_ 256            // fusion px tile
#define NEG_SLOPE_ 0.1f

// ws layout:
//   [0, 32MB)             float partial[B_][NPART_][C_][C_]   (d-permuted slabs)
//   [32MB, +64KB)         int   idxb[B_][C_][K_]
// slab layout: element (c, s) with s = 8*dq + j  holds corr[c][dq + 8*j]

// corr v9 (= R6 v3 + vectorized permuted stores): 8x8 register tile per
// thread (16 b128 reads per 256 fma). Each wave privately stages a 64x32-n
// slab (no block barriers -> compiler overlaps next-chunk loads with fma),
// processes 2 sub-chunks (64 n) into one f32 partial slab.
__global__ __launch_bounds__(256, 2) void corr_partial_kernel(
    const float* __restrict__ LR, const float* __restrict__ HR,
    float* __restrict__ partial)
{
    __shared__ float lrS[4][C_][SROW];   // 36.9 KB
    __shared__ float hrS[4][C_][SROW];   // 36.9 KB
    const int bid = blockIdx.x;          // 512 = B * 64
    const int b = bid >> 6;
    const int q = bid & 63;
    const int t = threadIdx.x;
    const int wv = t >> 6;
    const int lane = t & 63;
    const int cq = lane >> 3;            // 0..7
    const int dq = lane & 7;             // 0..7

    float acc[8][8] = {};

    #pragma unroll 1
    for (int s = 0; s < 2; ++s) {
        const int n0 = (((q * 4 + wv) << 1) + s) * 32;
        // stage this wave's 64x32 slabs (wave-private; compiler orders LDS WAR)
        #pragma unroll
        for (int i = 0; i < 8; ++i) {
            const int c = i * 8 + (lane >> 3);
            const int col = (lane & 7) * 4;
            *reinterpret_cast<float4*>(&lrS[wv][c][col]) =
                *reinterpret_cast<const float4*>(&LR[(size_t)(b * C_ + c) * HW_ + n0 + col]);
            *reinterpret_cast<float4*>(&hrS[wv][c][col]) =
                *reinterpret_cast<const float4*>(&HR[(size_t)(b * C_ + c) * HW_ + n0 + col]);
        }
        // compute: rows cq+8i / dq+8j; stride 36 -> 8 broadcast groups on
        // 8 distinct bank-quads per read instruction (conflict-free)
        #pragma unroll 2
        for (int nq = 0; nq < 8; ++nq) {
            float4 lv[8], hv[8];
            #pragma unroll
            for (int i = 0; i < 8; ++i)
                lv[i] = *reinterpret_cast<const float4*>(&lrS[wv][cq + 8 * i][nq * 4]);
            #pragma unroll
            for (int j = 0; j < 8; ++j)
                hv[j] = *reinterpret_cast<const float4*>(&hrS[wv][dq + 8 * j][nq * 4]);
            #pragma unroll
            for (int i = 0; i < 8; ++i)
                #pragma unroll
                for (int j = 0; j < 8; ++j) {
                    acc[i][j] = fmaf(lv[i].x, hv[j].x, acc[i][j]);
                    acc[i][j] = fmaf(lv[i].y, hv[j].y, acc[i][j]);
                    acc[i][j] = fmaf(lv[i].z, hv[j].z, acc[i][j]);
                    acc[i][j] = fmaf(lv[i].w, hv[j].w, acc[i][j]);
                }
        }
    }

    // permuted f4 stores: slab position s = 8*dq + j  <- acc[i][j]
    const int pid = q * 4 + wv;
    float* P = partial + (size_t)(b * NPART_ + pid) * (C_ * C_);
    #pragma unroll
    for (int i = 0; i < 8; ++i) {
        const int base = (cq + 8 * i) * C_ + 8 * dq;
        *reinterpret_cast<float4*>(&P[base]) =
            make_float4(acc[i][0], acc[i][1], acc[i][2], acc[i][3]);
        *reinterpret_cast<float4*>(&P[base + 4]) =
            make_float4(acc[i][4], acc[i][5], acc[i][6], acc[i][7]);
    }
}

// Reduce 256 partials per (b,c) in fixed order (f64, deterministic),
// un-permute (d = (s>>3) + 8*(s&7)), rank channels like lax.top_k
// (stable descending on true indices), emit indices.
__global__ __launch_bounds__(256) void rank_kernel(
    const float* __restrict__ partial, int* __restrict__ idxb)
{
    __shared__ double sh[4][C_];
    __shared__ double vals[C_];
    const int blk = blockIdx.x;     // b*64 + c
    const int b = blk >> 6;
    const int c = blk & 63;
    const int g = threadIdx.x >> 6;
    const int s = threadIdx.x & 63;

    double acc = 0.0;
    for (int k = 0; k < 64; ++k)
        acc += (double)partial[(size_t)(b * NPART_ + g * 64 + k) * (C_ * C_) + c * C_ + s];
    sh[g][s] = acc;
    __syncthreads();

    if (threadIdx.x < 64) {
        const int d = (s >> 3) + 8 * (s & 7);          // true channel
        vals[d] = ((sh[0][s] + sh[1][s]) + sh[2][s]) + sh[3][s];
    }
    __syncthreads();

    if (threadIdx.x < 64) {
        const int d = (s >> 3) + 8 * (s & 7);
        const double vd = vals[d];
        int r = 0;
        for (int j = 0; j < C_; ++j) {
            const double vj = vals[j];
            r += (int)((vj > vd) || (vj == vd && j < d));   // stable descending rank
        }
        if (r < K_) idxb[blk * K_ + r] = d;
    }
}

// Gather fusion: stage HR[64][256] px-slab in LDS; 8 waves x 8 c each;
// gather via ds_read_b128 (1 KB/wave-instr). (512,2): VGPR cap 128 (needs ~88);
// LDS 64KB already limits to 2 blocks/CU.
__global__ __launch_bounds__(512, 2) void fusion_gather_kernel(
    const float* __restrict__ HR, const float* __restrict__ LR,
    const int* __restrict__ idxb,
    const float* __restrict__ w1, const float* __restrict__ b1,
    const float* __restrict__ w2, const float* __restrict__ b2,
    float* __restrict__ out)
{
    __shared__ float hrS[C_][TILE_];   // 64 KB

    const int t = threadIdx.x;
    const int bid = blockIdx.x;        // 512 = B * (HW/TILE)
    const int b = bid >> 6;
    const int px0 = (bid & 63) * TILE_;

    const float* HRb = HR + (size_t)b * C_ * HW_;
    #pragma unroll
    for (int i = 0; i < 8; ++i) {
        const int f = i * 512 + t;
        const int c = f >> 6;
        const int qq = f & 63;
        *reinterpret_cast<float4*>(&hrS[c][qq * 4]) =
            *reinterpret_cast<const float4*>(&HRb[(size_t)c * HW_ + px0 + qq * 4]);
    }
    __syncthreads();

    const int wv = t >> 6;             // wave id -> c-octant
    const int lane = t & 63;
    const int p4 = lane * 4;           // this lane's 4 px within the tile

    const int* idxc = idxb + b * C_ * K_;
    const float w10 = w1[0];
    const float b1v = b1[0], w2v = w2[0], b2v = b2[0];

    #pragma unroll 1
    for (int ci = 0; ci < 8; ++ci) {
        const int c = wv * 8 + ci;
        const float4 l4 = *reinterpret_cast<const float4*>(
            &LR[(size_t)(b * C_ + c) * HW_ + px0 + p4]);         // issue early
        float acc[4] = {0.f, 0.f, 0.f, 0.f};
        float mx[4]  = {-1e30f, -1e30f, -1e30f, -1e30f};
        #pragma unroll
        for (int k = 0; k < K_; ++k) {
            const int d = idxc[c * K_ + k];          // uniform -> s_load
            const float4 h = *reinterpret_cast<const float4*>(&hrS[d][p4]);
            const float wk = w1[k + 1];              // uniform -> SGPR
            acc[0] = fmaf(h.x, wk, acc[0]);
            acc[1] = fmaf(h.y, wk, acc[1]);
            acc[2] = fmaf(h.z, wk, acc[2]);
            acc[3] = fmaf(h.w, wk, acc[3]);
            mx[0] = fmaxf(mx[0], h.x);
            mx[1] = fmaxf(mx[1], h.y);
            mx[2] = fmaxf(mx[2], h.z);
            mx[3] = fmaxf(mx[3], h.w);
        }
        const float l[4] = {l4.x, l4.y, l4.z, l4.w};
        float o[4];
        #pragma unroll
        for (int p = 0; p < 4; ++p) {
            float f = fmaf(w10, l[p], acc[p]) + b1v;
            f = f >= 0.f ? f : NEG_SLOPE_ * f;
            f = fmaf(w2v, f, b2v);
            const float s = 1.f / (1.f + __expf(-mx[p]));
            o[p] = f * (1.f + s);
        }
        *reinterpret_cast<float4*>(&out[(size_t)(b * C_ + c) * HW_ + px0 + p4]) =
            make_float4(o[0], o[1], o[2], o[3]);
    }
}

extern "C" void kernel_launch(void* const* d_in, const int* in_sizes, int n_in,
                              void* d_out, int out_size, void* d_ws, size_t ws_size,
                              hipStream_t stream)
{
    const float* HR = (const float*)d_in[0];
    const float* LR = (const float*)d_in[1];
    const float* w1 = (const float*)d_in[2];
    const float* b1 = (const float*)d_in[3];
    const float* w2 = (const float*)d_in[4];
    const float* b2 = (const float*)d_in[5];
    float* out = (float*)d_out;

    float* partial = (float*)d_ws;
    int* idxb = (int*)((char*)d_ws + (size_t)B_ * NPART_ * C_ * C_ * sizeof(float));

    corr_partial_kernel<<<B_ * 64, 256, 0, stream>>>(LR, HR, partial);
    rank_kernel<<<B_ * C_, 256, 0, stream>>>(partial, idxb);
    fusion_gather_kernel<<<B_ * (HW_ / TILE_), 512, 0, stream>>>(HR, LR, idxb, w1, b1, w2, b2, out);
}